// Round 1
// baseline (1323.148 us; speedup 1.0000x reference)
//
#include <hip/hip_runtime.h>
#include <hip/hip_bf16.h>

#define HDIM 1024
#define BS_TOT (2048 * 64)

typedef __bf16 bf16x8 __attribute__((ext_vector_type(8)));
typedef __bf16 bf16x4 __attribute__((ext_vector_type(4)));
typedef float  f32x4  __attribute__((ext_vector_type(4)));

__device__ __forceinline__ void async_load16(const void* g, void* l) {
  __builtin_amdgcn_global_load_lds(
      (const __attribute__((address_space(1))) void*)g,
      (__attribute__((address_space(3))) void*)l, 16, 0, 0);
}

// ---------------------------------------------------------------------------
// Transpose + fp32->bf16: out[n][k] = (bf16) in[k][n], 1024x1024
// ---------------------------------------------------------------------------
__global__ __launch_bounds__(256) void k_transpose_cvt(const float* __restrict__ in,
                                                       __bf16* __restrict__ out) {
  __shared__ float tile[32][33];
  const int bx = blockIdx.x * 32, by = blockIdx.y * 32;
  for (int i = threadIdx.y; i < 32; i += 8)
    tile[i][threadIdx.x] = in[(size_t)(by + i) * HDIM + bx + threadIdx.x];
  __syncthreads();
  for (int i = threadIdx.y; i < 32; i += 8)
    out[(size_t)(bx + i) * HDIM + by + threadIdx.x] = (__bf16)tile[threadIdx.x][i];
}

// ---------------------------------------------------------------------------
// GEMM: C[m][n] = (bf16)( A[m][:] (fp32, cvt->bf16) dot Bt[n][:] (bf16) + bias[n] )
// Tile 128x128, BK=64, 256 threads (4 waves, 2x2 of 64x64), mfma 16x16x32 bf16.
// LDS layout in 16B chunks, chunk (r,c) stored at physical r*8 + (c ^ (r&7)).
// A staged manually fp32->bf16; B staged with global_load_lds width 16.
// ---------------------------------------------------------------------------
__global__ __launch_bounds__(256) void k_gemm(const float* __restrict__ A,
                                              const __bf16* __restrict__ Bt,
                                              const float* __restrict__ bias,
                                              __bf16* __restrict__ C, int M) {
  __shared__ __bf16 sA[128 * 64];
  __shared__ __bf16 sB[128 * 64];
  const int t = threadIdx.x;
  const int lane = t & 63;
  const int quad = lane >> 4;
  const int w = t >> 6;
  const int wr = w >> 1, wc = w & 1;
  const int m0 = ((int)blockIdx.x >> 3) * 128;
  const int n0 = ((int)blockIdx.x & 7) * 128;
  (void)M;

  f32x4 acc[4][4];
  const f32x4 zero = {0.f, 0.f, 0.f, 0.f};
#pragma unroll
  for (int i = 0; i < 4; ++i)
#pragma unroll
    for (int j = 0; j < 4; ++j) acc[i][j] = zero;

  int rS[4], cS[4];
#pragma unroll
  for (int i = 0; i < 4; ++i) {
    int p = i * 256 + t;
    rS[i] = p >> 3;
    cS[i] = (p & 7) ^ (rS[i] & 7);
  }

  for (int kt = 0; kt < HDIM; kt += 64) {
    // B tile: async global->LDS (16B/lane), LDS slot = lane-order contiguous
#pragma unroll
    for (int i = 0; i < 4; ++i) {
      const __bf16* g = Bt + (size_t)(n0 + rS[i]) * HDIM + kt + cS[i] * 8;
      async_load16(g, sB + (i * 256 + (t & 192)) * 8);
    }
    // A tile: fp32 load, cvt to bf16, ds_write_b128
#pragma unroll
    for (int i = 0; i < 4; ++i) {
      const float* g = A + (size_t)(m0 + rS[i]) * HDIM + kt + cS[i] * 8;
      f32x4 v0 = *(const f32x4*)g;
      f32x4 v1 = *(const f32x4*)(g + 4);
      bf16x8 pk;
#pragma unroll
      for (int j = 0; j < 4; ++j) {
        pk[j] = (__bf16)v0[j];
        pk[j + 4] = (__bf16)v1[j];
      }
      *(bf16x8*)(sA + (i * 256 + t) * 8) = pk;
    }
    __syncthreads();
#pragma unroll
    for (int ks = 0; ks < 2; ++ks) {
      bf16x8 af[4], bv[4];
#pragma unroll
      for (int mi = 0; mi < 4; ++mi) {
        int r = wr * 64 + mi * 16 + (lane & 15);
        int c = ks * 4 + quad;
        int p = r * 8 + (c ^ (r & 7));
        af[mi] = *(const bf16x8*)(sA + p * 8);
      }
#pragma unroll
      for (int ni = 0; ni < 4; ++ni) {
        int r = wc * 64 + ni * 16 + (lane & 15);
        int c = ks * 4 + quad;
        int p = r * 8 + (c ^ (r & 7));
        bv[ni] = *(const bf16x8*)(sB + p * 8);
      }
#pragma unroll
      for (int mi = 0; mi < 4; ++mi)
#pragma unroll
        for (int ni = 0; ni < 4; ++ni)
          acc[mi][ni] = __builtin_amdgcn_mfma_f32_16x16x32_bf16(af[mi], bv[ni], acc[mi][ni], 0, 0, 0);
    }
    __syncthreads();
  }

  // epilogue: C/D layout col=lane&15, row=quad*4+reg  (m89-verified)
#pragma unroll
  for (int ni = 0; ni < 4; ++ni) {
    int col = n0 + wc * 64 + ni * 16 + (lane & 15);
    float bvs = bias[col];
#pragma unroll
    for (int mi = 0; mi < 4; ++mi) {
      int rb = m0 + wr * 64 + mi * 16 + quad * 4;
#pragma unroll
      for (int rg = 0; rg < 4; ++rg)
        C[(size_t)(rb + rg) * HDIM + col] = (__bf16)(acc[mi][ni][rg] + bvs);
    }
  }
}

// ---------------------------------------------------------------------------
// Fused: per-block one batch b. LN(qraw) per wave; for each s-row: LN(kraw),
// relu(q+k) dot Wb -> beta; then wave-64 masked softmax + scans.
// ---------------------------------------------------------------------------
__global__ __launch_bounds__(256) void k_fused(const __bf16* __restrict__ kraw,
                                               const __bf16* __restrict__ qraw,
                                               const float* __restrict__ gq,
                                               const float* __restrict__ betaq,
                                               const float* __restrict__ gk,
                                               const float* __restrict__ betak,
                                               const float* __restrict__ Wb,
                                               const float* __restrict__ bbp,
                                               const float* __restrict__ prev_p,
                                               float* __restrict__ out, int b0) {
  const int t = threadIdx.x, lane = t & 63, w = t >> 6;
  const int bl = blockIdx.x;
  const int bg = b0 + bl;
  __shared__ float betaLds[64];

  float vgk[16], vbk[16], vwb[16], qn[16];
  {
    float vq[16], vgq[16], vbq[16];
    const __bf16* qrow = qraw + (size_t)bg * HDIM;
    float s0 = 0.f, s1 = 0.f;
#pragma unroll
    for (int i = 0; i < 4; ++i) {
      int e = i * 256 + lane * 4;
      f32x4 g1 = *(const f32x4*)(gq + e);
      f32x4 b1 = *(const f32x4*)(betaq + e);
      f32x4 g2 = *(const f32x4*)(gk + e);
      f32x4 b2 = *(const f32x4*)(betak + e);
      f32x4 wv = *(const f32x4*)(Wb + e);
      bf16x4 qv = *(const bf16x4*)(qrow + e);
#pragma unroll
      for (int j = 0; j < 4; ++j) {
        vgq[i * 4 + j] = g1[j]; vbq[i * 4 + j] = b1[j];
        vgk[i * 4 + j] = g2[j]; vbk[i * 4 + j] = b2[j];
        vwb[i * 4 + j] = wv[j];
        float q = (float)qv[j];
        vq[i * 4 + j] = q;
        s0 += q; s1 += q * q;
      }
    }
#pragma unroll
    for (int m = 32; m; m >>= 1) { s0 += __shfl_xor(s0, m); s1 += __shfl_xor(s1, m); }
    float mq = s0 * (1.f / 1024.f);
    float vv = s1 * (1.f / 1024.f) - mq * mq;
    float rq = rsqrtf(vv + 1e-5f);
#pragma unroll
    for (int j = 0; j < 16; ++j) qn[j] = (vq[j] - mq) * rq * vgq[j] + vbq[j];
  }
  const float bb = bbp[0];

  for (int it = 0; it < 16; ++it) {
    int s = w * 16 + it;
    const __bf16* xrow = kraw + ((size_t)bl * 64 + s) * HDIM;
    float xv[16];
    float s0 = 0.f, s1 = 0.f;
#pragma unroll
    for (int i = 0; i < 4; ++i) {
      bf16x4 v = *(const bf16x4*)(xrow + i * 256 + lane * 4);
#pragma unroll
      for (int j = 0; j < 4; ++j) {
        float x = (float)v[j];
        xv[i * 4 + j] = x;
        s0 += x; s1 += x * x;
      }
    }
#pragma unroll
    for (int m = 32; m; m >>= 1) { s0 += __shfl_xor(s0, m); s1 += __shfl_xor(s1, m); }
    float mean = s0 * (1.f / 1024.f);
    float var = s1 * (1.f / 1024.f) - mean * mean;
    float rstd = rsqrtf(var + 1e-5f);
    float d = 0.f;
#pragma unroll
    for (int j = 0; j < 16; ++j) {
      float h = qn[j] + (xv[j] - mean) * rstd * vgk[j] + vbk[j];
      h = fmaxf(h, 0.f);
      d += h * vwb[j];
    }
#pragma unroll
    for (int m = 32; m; m >>= 1) d += __shfl_xor(d, m);
    if (lane == 0) betaLds[s] = (d + bb) * 0.03125f;
  }
  __syncthreads();

  if (t < 64) {
    float beta = betaLds[lane];
    float mx = beta;
#pragma unroll
    for (int m = 32; m; m >>= 1) mx = fmaxf(mx, __shfl_xor(mx, m));
    float x = __expf(beta - mx);
    float pp = prev_p[(size_t)bg * 64 + lane];
    float cpp = pp;
    for (int off = 1; off < 64; off <<= 1) {
      float u = __shfl_up(cpp, off);
      if (lane >= off) cpp += u;
    }
    float nxt = __shfl_down(cpp, 1);
    float mask = (lane == 63) ? 1.0f : ((nxt < 1e-5f) ? 0.0f : nxt);
    float xm = x * mask;
    float den = xm;
#pragma unroll
    for (int m = 32; m; m >>= 1) den += __shfl_xor(den, m);
    den = fmaxf(den, 1e-12f);
    float p = xm / den;
    float cp = p;
    for (int off = 1; off < 64; off <<= 1) {
      float u = __shfl_up(cp, off);
      if (lane >= off) cp += u;
    }
    float tot = __shfl(cp, 63);
    float rcp = tot - cp + p;
    size_t idx = (size_t)bg * 64 + lane;
    out[idx] = cp;
    out[BS_TOT + idx] = rcp;
    out[2 * BS_TOT + idx] = p;
  }
}

extern "C" void kernel_launch(void* const* d_in, const int* in_sizes, int n_in,
                              void* d_out, int out_size, void* d_ws, size_t ws_size,
                              hipStream_t stream) {
  (void)in_sizes; (void)n_in; (void)out_size; (void)ws_size;
  const float* in_val     = (const float*)d_in[0];
  const float* prev_out_M = (const float*)d_in[1];
  const float* prev_p     = (const float*)d_in[2];
  const float* Wq         = (const float*)d_in[3];
  const float* bq         = (const float*)d_in[4];
  const float* gq         = (const float*)d_in[5];
  const float* betaq      = (const float*)d_in[6];
  const float* Wk         = (const float*)d_in[7];
  const float* bk         = (const float*)d_in[8];
  const float* gk         = (const float*)d_in[9];
  const float* betak      = (const float*)d_in[10];
  const float* Wb         = (const float*)d_in[11];
  const float* bb         = (const float*)d_in[12];
  float* out = (float*)d_out;

  char* ws = (char*)d_ws;
  __bf16* WqT  = (__bf16*)(ws);                    // 2 MB
  __bf16* WkT  = (__bf16*)(ws + (size_t)(2 << 20)); // 2 MB
  __bf16* qraw = (__bf16*)(ws + (size_t)(4 << 20)); // 4 MB
  __bf16* kraw = (__bf16*)(ws + (size_t)(8 << 20)); // 64 MB (one chunk)

  dim3 tb(32, 8);
  k_transpose_cvt<<<dim3(32, 32), tb, 0, stream>>>(Wq, WqT);
  k_transpose_cvt<<<dim3(32, 32), tb, 0, stream>>>(Wk, WkT);
  k_gemm<<<(2048 / 128) * 8, 256, 0, stream>>>(in_val, WqT, bq, qraw, 2048);

  const int MCH = 32768;  // rows per chunk (512 batches)
  for (int c = 0; c < 4; ++c) {
    k_gemm<<<(MCH / 128) * 8, 256, 0, stream>>>(
        prev_out_M + (size_t)c * MCH * HDIM, WkT, bk, kraw, MCH);
    k_fused<<<512, 256, 0, stream>>>(kraw, qraw, gq, betaq, gk, betak, Wb, bb,
                                     prev_p, out, c * 512);
  }
}

// Round 2
// 1207.706 us; speedup vs baseline: 1.0956x; 1.0956x over previous
//
#include <hip/hip_runtime.h>
#include <hip/hip_bf16.h>

#define HDIM 1024
#define BS_TOT (2048 * 64)

typedef __bf16 bf16x8 __attribute__((ext_vector_type(8)));
typedef __bf16 bf16x4 __attribute__((ext_vector_type(4)));
typedef float  f32x4  __attribute__((ext_vector_type(4)));

__device__ __forceinline__ void async_load16(const void* g, void* l) {
  __builtin_amdgcn_global_load_lds(
      (const __attribute__((address_space(1))) void*)g,
      (__attribute__((address_space(3))) void*)l, 16, 0, 0);
}

// ---------------------------------------------------------------------------
// Streaming fp32 -> bf16 convert, 8 elems/thread (32B in, 16B out per lane)
// ---------------------------------------------------------------------------
__global__ __launch_bounds__(256) void k_cvt8(const float* __restrict__ in,
                                              __bf16* __restrict__ out) {
  size_t i = ((size_t)blockIdx.x * 256 + threadIdx.x) * 8;
  f32x4 v0 = *(const f32x4*)(in + i);
  f32x4 v1 = *(const f32x4*)(in + i + 4);
  bf16x8 pk;
#pragma unroll
  for (int j = 0; j < 4; ++j) {
    pk[j] = (__bf16)v0[j];
    pk[j + 4] = (__bf16)v1[j];
  }
  *(bf16x8*)(out + i) = pk;
}

// ---------------------------------------------------------------------------
// Transpose + fp32->bf16: out[n][k] = (bf16) in[k][n], 1024x1024
// ---------------------------------------------------------------------------
__global__ __launch_bounds__(256) void k_transpose_cvt(const float* __restrict__ in,
                                                       __bf16* __restrict__ out) {
  __shared__ float tile[32][33];
  const int bx = blockIdx.x * 32, by = blockIdx.y * 32;
  for (int i = threadIdx.y; i < 32; i += 8)
    tile[i][threadIdx.x] = in[(size_t)(by + i) * HDIM + bx + threadIdx.x];
  __syncthreads();
  for (int i = threadIdx.y; i < 32; i += 8)
    out[(size_t)(bx + i) * HDIM + by + threadIdx.x] = (__bf16)tile[threadIdx.x][i];
}

// ---------------------------------------------------------------------------
// GEMM: C[m][n] = (bf16)( A[m][:] dot Bt[n][:] + bias[n] ), A,Bt both bf16 [.][k]
// Tile 128x128, BK=64, 256 threads (4 waves, 2x2 of 64x64), mfma 16x16x32 bf16.
// LDS layout in 16B chunks, chunk (r,c) stored at physical r*8 + (c ^ (r&7)).
// Both A and B staged with global_load_lds width=16 (m97 structure).
// ---------------------------------------------------------------------------
__global__ __launch_bounds__(256) void k_gemm(const __bf16* __restrict__ A,
                                              const __bf16* __restrict__ Bt,
                                              const float* __restrict__ bias,
                                              __bf16* __restrict__ C) {
  __shared__ __bf16 sA[128 * 64];
  __shared__ __bf16 sB[128 * 64];
  const int t = threadIdx.x;
  const int lane = t & 63;
  const int quad = lane >> 4;
  const int w = t >> 6;
  const int wr = w >> 1, wc = w & 1;
  const int m0 = ((int)blockIdx.x >> 3) * 128;
  const int n0 = ((int)blockIdx.x & 7) * 128;

  f32x4 acc[4][4];
  const f32x4 zero = {0.f, 0.f, 0.f, 0.f};
#pragma unroll
  for (int i = 0; i < 4; ++i)
#pragma unroll
    for (int j = 0; j < 4; ++j) acc[i][j] = zero;

  int rS[4], cS[4];
#pragma unroll
  for (int i = 0; i < 4; ++i) {
    int p = i * 256 + t;
    rS[i] = p >> 3;
    cS[i] = (p & 7) ^ (rS[i] & 7);
  }

  for (int kt = 0; kt < HDIM; kt += 64) {
#pragma unroll
    for (int i = 0; i < 4; ++i) {
      async_load16(A + (size_t)(m0 + rS[i]) * HDIM + kt + cS[i] * 8,
                   sA + (i * 256 + (t & 192)) * 8);
      async_load16(Bt + (size_t)(n0 + rS[i]) * HDIM + kt + cS[i] * 8,
                   sB + (i * 256 + (t & 192)) * 8);
    }
    __syncthreads();
#pragma unroll
    for (int ks = 0; ks < 2; ++ks) {
      bf16x8 af[4], bv[4];
#pragma unroll
      for (int mi = 0; mi < 4; ++mi) {
        int r = wr * 64 + mi * 16 + (lane & 15);
        int c = ks * 4 + quad;
        int p = r * 8 + (c ^ (r & 7));
        af[mi] = *(const bf16x8*)(sA + p * 8);
      }
#pragma unroll
      for (int ni = 0; ni < 4; ++ni) {
        int r = wc * 64 + ni * 16 + (lane & 15);
        int c = ks * 4 + quad;
        int p = r * 8 + (c ^ (r & 7));
        bv[ni] = *(const bf16x8*)(sB + p * 8);
      }
#pragma unroll
      for (int mi = 0; mi < 4; ++mi)
#pragma unroll
        for (int ni = 0; ni < 4; ++ni)
          acc[mi][ni] = __builtin_amdgcn_mfma_f32_16x16x32_bf16(af[mi], bv[ni], acc[mi][ni], 0, 0, 0);
    }
    __syncthreads();
  }

  // epilogue: C/D layout col=lane&15, row=quad*4+reg  (m89-verified)
#pragma unroll
  for (int ni = 0; ni < 4; ++ni) {
    int col = n0 + wc * 64 + ni * 16 + (lane & 15);
    float bvs = bias[col];
#pragma unroll
    for (int mi = 0; mi < 4; ++mi) {
      int rb = m0 + wr * 64 + mi * 16 + quad * 4;
#pragma unroll
      for (int rg = 0; rg < 4; ++rg)
        C[(size_t)(rb + rg) * HDIM + col] = (__bf16)(acc[mi][ni][rg] + bvs);
    }
  }
}

// ---------------------------------------------------------------------------
// Fused: per-block one batch b. LN(qraw) per wave; for each s-row: LN(kraw),
// relu(q+k) dot Wb -> beta; then wave-64 masked softmax + scans.
// ---------------------------------------------------------------------------
__global__ __launch_bounds__(256) void k_fused(const __bf16* __restrict__ kraw,
                                               const __bf16* __restrict__ qraw,
                                               const float* __restrict__ gq,
                                               const float* __restrict__ betaq,
                                               const float* __restrict__ gk,
                                               const float* __restrict__ betak,
                                               const float* __restrict__ Wb,
                                               const float* __restrict__ bbp,
                                               const float* __restrict__ prev_p,
                                               float* __restrict__ out, int b0) {
  const int t = threadIdx.x, lane = t & 63, w = t >> 6;
  const int bl = blockIdx.x;
  const int bg = b0 + bl;
  __shared__ float betaLds[64];

  float vgk[16], vbk[16], vwb[16], qn[16];
  {
    float vq[16], vgq[16], vbq[16];
    const __bf16* qrow = qraw + (size_t)bg * HDIM;
    float s0 = 0.f, s1 = 0.f;
#pragma unroll
    for (int i = 0; i < 4; ++i) {
      int e = i * 256 + lane * 4;
      f32x4 g1 = *(const f32x4*)(gq + e);
      f32x4 b1 = *(const f32x4*)(betaq + e);
      f32x4 g2 = *(const f32x4*)(gk + e);
      f32x4 b2 = *(const f32x4*)(betak + e);
      f32x4 wv = *(const f32x4*)(Wb + e);
      bf16x4 qv = *(const bf16x4*)(qrow + e);
#pragma unroll
      for (int j = 0; j < 4; ++j) {
        vgq[i * 4 + j] = g1[j]; vbq[i * 4 + j] = b1[j];
        vgk[i * 4 + j] = g2[j]; vbk[i * 4 + j] = b2[j];
        vwb[i * 4 + j] = wv[j];
        float q = (float)qv[j];
        vq[i * 4 + j] = q;
        s0 += q; s1 += q * q;
      }
    }
#pragma unroll
    for (int m = 32; m; m >>= 1) { s0 += __shfl_xor(s0, m); s1 += __shfl_xor(s1, m); }
    float mq = s0 * (1.f / 1024.f);
    float vv = s1 * (1.f / 1024.f) - mq * mq;
    float rq = rsqrtf(vv + 1e-5f);
#pragma unroll
    for (int j = 0; j < 16; ++j) qn[j] = (vq[j] - mq) * rq * vgq[j] + vbq[j];
  }
  const float bb = bbp[0];

  for (int it = 0; it < 16; ++it) {
    int s = w * 16 + it;
    const __bf16* xrow = kraw + ((size_t)bl * 64 + s) * HDIM;
    float xv[16];
    float s0 = 0.f, s1 = 0.f;
#pragma unroll
    for (int i = 0; i < 4; ++i) {
      bf16x4 v = *(const bf16x4*)(xrow + i * 256 + lane * 4);
#pragma unroll
      for (int j = 0; j < 4; ++j) {
        float x = (float)v[j];
        xv[i * 4 + j] = x;
        s0 += x; s1 += x * x;
      }
    }
#pragma unroll
    for (int m = 32; m; m >>= 1) { s0 += __shfl_xor(s0, m); s1 += __shfl_xor(s1, m); }
    float mean = s0 * (1.f / 1024.f);
    float var = s1 * (1.f / 1024.f) - mean * mean;
    float rstd = rsqrtf(var + 1e-5f);
    float d = 0.f;
#pragma unroll
    for (int j = 0; j < 16; ++j) {
      float h = qn[j] + (xv[j] - mean) * rstd * vgk[j] + vbk[j];
      h = fmaxf(h, 0.f);
      d += h * vwb[j];
    }
#pragma unroll
    for (int m = 32; m; m >>= 1) d += __shfl_xor(d, m);
    if (lane == 0) betaLds[s] = (d + bb) * 0.03125f;
  }
  __syncthreads();

  if (t < 64) {
    float beta = betaLds[lane];
    float mx = beta;
#pragma unroll
    for (int m = 32; m; m >>= 1) mx = fmaxf(mx, __shfl_xor(mx, m));
    float x = __expf(beta - mx);
    float pp = prev_p[(size_t)bg * 64 + lane];
    float cpp = pp;
    for (int off = 1; off < 64; off <<= 1) {
      float u = __shfl_up(cpp, off);
      if (lane >= off) cpp += u;
    }
    float nxt = __shfl_down(cpp, 1);
    float mask = (lane == 63) ? 1.0f : ((nxt < 1e-5f) ? 0.0f : nxt);
    float xm = x * mask;
    float den = xm;
#pragma unroll
    for (int m = 32; m; m >>= 1) den += __shfl_xor(den, m);
    den = fmaxf(den, 1e-12f);
    float p = xm / den;
    float cp = p;
    for (int off = 1; off < 64; off <<= 1) {
      float u = __shfl_up(cp, off);
      if (lane >= off) cp += u;
    }
    float tot = __shfl(cp, 63);
    float rcp = tot - cp + p;
    size_t idx = (size_t)bg * 64 + lane;
    out[idx] = cp;
    out[BS_TOT + idx] = rcp;
    out[2 * BS_TOT + idx] = p;
  }
}

extern "C" void kernel_launch(void* const* d_in, const int* in_sizes, int n_in,
                              void* d_out, int out_size, void* d_ws, size_t ws_size,
                              hipStream_t stream) {
  (void)in_sizes; (void)n_in; (void)out_size; (void)ws_size;
  const float* in_val     = (const float*)d_in[0];
  const float* prev_out_M = (const float*)d_in[1];
  const float* prev_p     = (const float*)d_in[2];
  const float* Wq         = (const float*)d_in[3];
  const float* bq         = (const float*)d_in[4];
  const float* gq         = (const float*)d_in[5];
  const float* betaq      = (const float*)d_in[6];
  const float* Wk         = (const float*)d_in[7];
  const float* bk         = (const float*)d_in[8];
  const float* gk         = (const float*)d_in[9];
  const float* betak      = (const float*)d_in[10];
  const float* Wb         = (const float*)d_in[11];
  const float* bb         = (const float*)d_in[12];
  float* out = (float*)d_out;

  char* ws = (char*)d_ws;
  __bf16* WqT  = (__bf16*)(ws);                      // 2 MB
  __bf16* WkT  = (__bf16*)(ws + (size_t)(2  << 20)); // 2 MB
  __bf16* qbf  = (__bf16*)(ws + (size_t)(4  << 20)); // 4 MB  (in_val bf16)
  __bf16* qraw = (__bf16*)(ws + (size_t)(8  << 20)); // 4 MB
  __bf16* Abf  = (__bf16*)(ws + (size_t)(16 << 20)); // 64 MB (A chunk bf16)
  __bf16* kraw = (__bf16*)(ws + (size_t)(80 << 20)); // 64 MB (one chunk)

  dim3 tb(32, 8);
  k_transpose_cvt<<<dim3(32, 32), tb, 0, stream>>>(Wq, WqT);
  k_transpose_cvt<<<dim3(32, 32), tb, 0, stream>>>(Wk, WkT);
  k_cvt8<<<(2048 * HDIM) / (8 * 256), 256, 0, stream>>>(in_val, qbf);
  k_gemm<<<(2048 / 128) * 8, 256, 0, stream>>>(qbf, WqT, bq, qraw);

  const int MCH = 32768;  // rows per chunk (512 batches)
  for (int c = 0; c < 4; ++c) {
    k_cvt8<<<((size_t)MCH * HDIM) / (8 * 256), 256, 0, stream>>>(
        prev_out_M + (size_t)c * MCH * HDIM, Abf);
    k_gemm<<<(MCH / 128) * 8, 256, 0, stream>>>(Abf, WkT, bk, kraw);
    k_fused<<<512, 256, 0, stream>>>(kraw, qraw, gq, betaq, gk, betak, Wb, bb,
                                     prev_p, out, c * 512);
  }
}

// Round 3
// 1165.092 us; speedup vs baseline: 1.1357x; 1.0366x over previous
//
#include <hip/hip_runtime.h>
#include <hip/hip_bf16.h>

#define HDIM 1024
#define BS_TOT (2048 * 64)

typedef __bf16 bf16x8 __attribute__((ext_vector_type(8)));
typedef __bf16 bf16x4 __attribute__((ext_vector_type(4)));
typedef float  f32x4  __attribute__((ext_vector_type(4)));

__device__ __forceinline__ void async_load16(const void* g, void* l) {
  __builtin_amdgcn_global_load_lds(
      (const __attribute__((address_space(1))) void*)g,
      (__attribute__((address_space(3))) void*)l, 16, 0, 0);
}

// ---------------------------------------------------------------------------
// Streaming fp32 -> bf16 convert, 8 elems/thread (32B in, 16B out per lane)
// ---------------------------------------------------------------------------
__global__ __launch_bounds__(256) void k_cvt8(const float* __restrict__ in,
                                              __bf16* __restrict__ out) {
  size_t i = ((size_t)blockIdx.x * 256 + threadIdx.x) * 8;
  f32x4 v0 = *(const f32x4*)(in + i);
  f32x4 v1 = *(const f32x4*)(in + i + 4);
  bf16x8 pk;
#pragma unroll
  for (int j = 0; j < 4; ++j) {
    pk[j] = (__bf16)v0[j];
    pk[j + 4] = (__bf16)v1[j];
  }
  *(bf16x8*)(out + i) = pk;
}

// ---------------------------------------------------------------------------
// Transpose + fp32->bf16: out[n][k] = (bf16) in[k][n], 1024x1024
// ---------------------------------------------------------------------------
__global__ __launch_bounds__(256) void k_transpose_cvt(const float* __restrict__ in,
                                                       __bf16* __restrict__ out) {
  __shared__ float tile[32][33];
  const int bx = blockIdx.x * 32, by = blockIdx.y * 32;
  for (int i = threadIdx.y; i < 32; i += 8)
    tile[i][threadIdx.x] = in[(size_t)(by + i) * HDIM + bx + threadIdx.x];
  __syncthreads();
  for (int i = threadIdx.y; i < 32; i += 8)
    out[(size_t)(bx + i) * HDIM + by + threadIdx.x] = (__bf16)tile[threadIdx.x][i];
}

// ---------------------------------------------------------------------------
// GEMM: C[m][n] = (bf16)( A[m][:] dot Bt[n][:] + bias[n] ), A,Bt both bf16 [.][k]
// Tile 128x128, BK=64, 256 threads (4 waves, 2x2 of 64x64), mfma 16x16x32 bf16.
// Block decode: m = b & (2^mshift - 1), n = b >> mshift  (m-tile count = 2^mshift,
// a multiple of 8) -> XCD = b%8 = m%8: all 8 n-blocks of an m-tile share one XCD,
// dispatched 2^mshift apart; ~3 n-layers co-resident => A-tile L2 reuse.
// ---------------------------------------------------------------------------
__global__ __launch_bounds__(256) void k_gemm(const __bf16* __restrict__ A,
                                              const __bf16* __restrict__ Bt,
                                              const float* __restrict__ bias,
                                              __bf16* __restrict__ C, int mshift) {
  __shared__ __bf16 sA[128 * 64];
  __shared__ __bf16 sB[128 * 64];
  const int t = threadIdx.x;
  const int lane = t & 63;
  const int quad = lane >> 4;
  const int w = t >> 6;
  const int wr = w >> 1, wc = w & 1;
  const int b = (int)blockIdx.x;
  const int m0 = (b & ((1 << mshift) - 1)) * 128;
  const int n0 = (b >> mshift) * 128;

  f32x4 acc[4][4];
  const f32x4 zero = {0.f, 0.f, 0.f, 0.f};
#pragma unroll
  for (int i = 0; i < 4; ++i)
#pragma unroll
    for (int j = 0; j < 4; ++j) acc[i][j] = zero;

  int rS[4], cS[4];
#pragma unroll
  for (int i = 0; i < 4; ++i) {
    int p = i * 256 + t;
    rS[i] = p >> 3;
    cS[i] = (p & 7) ^ (rS[i] & 7);
  }

  for (int kt = 0; kt < HDIM; kt += 64) {
#pragma unroll
    for (int i = 0; i < 4; ++i) {
      async_load16(A + (size_t)(m0 + rS[i]) * HDIM + kt + cS[i] * 8,
                   sA + (i * 256 + (t & 192)) * 8);
      async_load16(Bt + (size_t)(n0 + rS[i]) * HDIM + kt + cS[i] * 8,
                   sB + (i * 256 + (t & 192)) * 8);
    }
    __syncthreads();
#pragma unroll
    for (int ks = 0; ks < 2; ++ks) {
      bf16x8 af[4], bv[4];
#pragma unroll
      for (int mi = 0; mi < 4; ++mi) {
        int r = wr * 64 + mi * 16 + (lane & 15);
        int c = ks * 4 + quad;
        int p = r * 8 + (c ^ (r & 7));
        af[mi] = *(const bf16x8*)(sA + p * 8);
      }
#pragma unroll
      for (int ni = 0; ni < 4; ++ni) {
        int r = wc * 64 + ni * 16 + (lane & 15);
        int c = ks * 4 + quad;
        int p = r * 8 + (c ^ (r & 7));
        bv[ni] = *(const bf16x8*)(sB + p * 8);
      }
#pragma unroll
      for (int mi = 0; mi < 4; ++mi)
#pragma unroll
        for (int ni = 0; ni < 4; ++ni)
          acc[mi][ni] = __builtin_amdgcn_mfma_f32_16x16x32_bf16(af[mi], bv[ni], acc[mi][ni], 0, 0, 0);
    }
    __syncthreads();
  }

  // epilogue: C/D layout col=lane&15, row=quad*4+reg  (m89-verified)
#pragma unroll
  for (int ni = 0; ni < 4; ++ni) {
    int col = n0 + wc * 64 + ni * 16 + (lane & 15);
    float bvs = bias[col];
#pragma unroll
    for (int mi = 0; mi < 4; ++mi) {
      int rb = m0 + wr * 64 + mi * 16 + quad * 4;
#pragma unroll
      for (int rg = 0; rg < 4; ++rg)
        C[(size_t)(rb + rg) * HDIM + col] = (__bf16)(acc[mi][ni][rg] + bvs);
    }
  }
}

// ---------------------------------------------------------------------------
// Fused: per-block one batch b. LN(qraw) per wave; for each s-row: LN(kraw),
// relu(q+k) dot Wb -> beta; then wave-64 masked softmax + scans.
// ---------------------------------------------------------------------------
__global__ __launch_bounds__(256) void k_fused(const __bf16* __restrict__ kraw,
                                               const __bf16* __restrict__ qraw,
                                               const float* __restrict__ gq,
                                               const float* __restrict__ betaq,
                                               const float* __restrict__ gk,
                                               const float* __restrict__ betak,
                                               const float* __restrict__ Wb,
                                               const float* __restrict__ bbp,
                                               const float* __restrict__ prev_p,
                                               float* __restrict__ out, int b0) {
  const int t = threadIdx.x, lane = t & 63, w = t >> 6;
  const int bl = blockIdx.x;
  const int bg = b0 + bl;
  __shared__ float betaLds[64];

  float vgk[16], vbk[16], vwb[16], qn[16];
  {
    float vq[16], vgq[16], vbq[16];
    const __bf16* qrow = qraw + (size_t)bg * HDIM;
    float s0 = 0.f, s1 = 0.f;
#pragma unroll
    for (int i = 0; i < 4; ++i) {
      int e = i * 256 + lane * 4;
      f32x4 g1 = *(const f32x4*)(gq + e);
      f32x4 b1 = *(const f32x4*)(betaq + e);
      f32x4 g2 = *(const f32x4*)(gk + e);
      f32x4 b2 = *(const f32x4*)(betak + e);
      f32x4 wv = *(const f32x4*)(Wb + e);
      bf16x4 qv = *(const bf16x4*)(qrow + e);
#pragma unroll
      for (int j = 0; j < 4; ++j) {
        vgq[i * 4 + j] = g1[j]; vbq[i * 4 + j] = b1[j];
        vgk[i * 4 + j] = g2[j]; vbk[i * 4 + j] = b2[j];
        vwb[i * 4 + j] = wv[j];
        float q = (float)qv[j];
        vq[i * 4 + j] = q;
        s0 += q; s1 += q * q;
      }
    }
#pragma unroll
    for (int m = 32; m; m >>= 1) { s0 += __shfl_xor(s0, m); s1 += __shfl_xor(s1, m); }
    float mq = s0 * (1.f / 1024.f);
    float vv = s1 * (1.f / 1024.f) - mq * mq;
    float rq = rsqrtf(vv + 1e-5f);
#pragma unroll
    for (int j = 0; j < 16; ++j) qn[j] = (vq[j] - mq) * rq * vgq[j] + vbq[j];
  }
  const float bb = bbp[0];

  for (int it = 0; it < 16; ++it) {
    int s = w * 16 + it;
    const __bf16* xrow = kraw + ((size_t)bl * 64 + s) * HDIM;
    float xv[16];
    float s0 = 0.f, s1 = 0.f;
#pragma unroll
    for (int i = 0; i < 4; ++i) {
      bf16x4 v = *(const bf16x4*)(xrow + i * 256 + lane * 4);
#pragma unroll
      for (int j = 0; j < 4; ++j) {
        float x = (float)v[j];
        xv[i * 4 + j] = x;
        s0 += x; s1 += x * x;
      }
    }
#pragma unroll
    for (int m = 32; m; m >>= 1) { s0 += __shfl_xor(s0, m); s1 += __shfl_xor(s1, m); }
    float mean = s0 * (1.f / 1024.f);
    float var = s1 * (1.f / 1024.f) - mean * mean;
    float rstd = rsqrtf(var + 1e-5f);
    float d = 0.f;
#pragma unroll
    for (int j = 0; j < 16; ++j) {
      float h = qn[j] + (xv[j] - mean) * rstd * vgk[j] + vbk[j];
      h = fmaxf(h, 0.f);
      d += h * vwb[j];
    }
#pragma unroll
    for (int m = 32; m; m >>= 1) d += __shfl_xor(d, m);
    if (lane == 0) betaLds[s] = (d + bb) * 0.03125f;
  }
  __syncthreads();

  if (t < 64) {
    float beta = betaLds[lane];
    float mx = beta;
#pragma unroll
    for (int m = 32; m; m >>= 1) mx = fmaxf(mx, __shfl_xor(mx, m));
    float x = __expf(beta - mx);
    float pp = prev_p[(size_t)bg * 64 + lane];
    float cpp = pp;
    for (int off = 1; off < 64; off <<= 1) {
      float u = __shfl_up(cpp, off);
      if (lane >= off) cpp += u;
    }
    float nxt = __shfl_down(cpp, 1);
    float mask = (lane == 63) ? 1.0f : ((nxt < 1e-5f) ? 0.0f : nxt);
    float xm = x * mask;
    float den = xm;
#pragma unroll
    for (int m = 32; m; m >>= 1) den += __shfl_xor(den, m);
    den = fmaxf(den, 1e-12f);
    float p = xm / den;
    float cp = p;
    for (int off = 1; off < 64; off <<= 1) {
      float u = __shfl_up(cp, off);
      if (lane >= off) cp += u;
    }
    float tot = __shfl(cp, 63);
    float rcp = tot - cp + p;
    size_t idx = (size_t)bg * 64 + lane;
    out[idx] = cp;
    out[BS_TOT + idx] = rcp;
    out[2 * BS_TOT + idx] = p;
  }
}

extern "C" void kernel_launch(void* const* d_in, const int* in_sizes, int n_in,
                              void* d_out, int out_size, void* d_ws, size_t ws_size,
                              hipStream_t stream) {
  (void)in_sizes; (void)n_in; (void)out_size; (void)ws_size;
  const float* in_val     = (const float*)d_in[0];
  const float* prev_out_M = (const float*)d_in[1];
  const float* prev_p     = (const float*)d_in[2];
  const float* Wq         = (const float*)d_in[3];
  const float* bq         = (const float*)d_in[4];
  const float* gq         = (const float*)d_in[5];
  const float* betaq      = (const float*)d_in[6];
  const float* Wk         = (const float*)d_in[7];
  const float* bk         = (const float*)d_in[8];
  const float* gk         = (const float*)d_in[9];
  const float* betak      = (const float*)d_in[10];
  const float* Wb         = (const float*)d_in[11];
  const float* bb         = (const float*)d_in[12];
  float* out = (float*)d_out;

  char* ws = (char*)d_ws;
  __bf16* WqT  = (__bf16*)(ws);                      // 2 MB
  __bf16* WkT  = (__bf16*)(ws + (size_t)(2  << 20)); // 2 MB
  __bf16* qbf  = (__bf16*)(ws + (size_t)(4  << 20)); // 4 MB  (in_val bf16)
  __bf16* qraw = (__bf16*)(ws + (size_t)(8  << 20)); // 4 MB
  __bf16* Abf  = (__bf16*)(ws + (size_t)(16 << 20)); // 64 MB (A chunk bf16)
  __bf16* kraw = (__bf16*)(ws + (size_t)(80 << 20)); // 64 MB (one chunk)

  dim3 tb(32, 8);
  k_transpose_cvt<<<dim3(32, 32), tb, 0, stream>>>(Wq, WqT);
  k_transpose_cvt<<<dim3(32, 32), tb, 0, stream>>>(Wk, WkT);
  k_cvt8<<<(2048 * HDIM) / (8 * 256), 256, 0, stream>>>(in_val, qbf);
  // q GEMM: 16 m-tiles (mshift=4), 8 n-tiles
  k_gemm<<<16 * 8, 256, 0, stream>>>(qbf, WqT, bq, qraw, 4);

  const int MCH = 32768;  // rows per chunk (512 batches); 256 m-tiles (mshift=8)
  for (int c = 0; c < 4; ++c) {
    k_cvt8<<<((size_t)MCH * HDIM) / (8 * 256), 256, 0, stream>>>(
        prev_out_M + (size_t)c * MCH * HDIM, Abf);
    k_gemm<<<256 * 8, 256, 0, stream>>>(Abf, WkT, bk, kraw, 8);
    k_fused<<<512, 256, 0, stream>>>(kraw, qraw, gq, betaq, gk, betak, Wb, bb,
                                     prev_p, out, c * 512);
  }
}